// Round 5
// baseline (248.333 us; speedup 1.0000x reference)
//
#include <hip/hip_runtime.h>
#include <hip/hip_bf16.h>

// Round 5: fuse k_xt into k_envlstm (k_step), precompute sense table.
//  - k_setup: pair geometry + sense table sv_g[pair][20] (f32, 10.5MB) + Wmf.
//  - k_f0: unchanged (verified).
//  - k_step x5: per block (16 atoms, 512 thr): stage xin/h/nb -> xt for all
//    128 molecule atoms (8x redundant, cheap) -> env (f32) -> bf16 pack ->
//    MFMA GEMM K=864 -> LSTM -> x0/out. 7 launches total (was 13).

#define DEG 32
#define NA 4096
#define NP 131072

typedef __hip_bfloat16 bf16;
typedef __attribute__((ext_vector_type(8))) short short8v;
typedef __attribute__((ext_vector_type(4))) float f32x4;

__device__ __forceinline__ float sigmoidf_(float x){ return 1.f/(1.f+expf(-x)); }
__device__ __forceinline__ float softplusf_(float x){ return fmaxf(x,0.f) + log1pf(expf(-fabsf(x))); }
// mu_s = linspace(1/5, 1/0.7, 20); sigma = (1/0.7-1/5)/20
__device__ __forceinline__ float senseval(float ivd, float cu, int s){
  float mu = 0.2f + (float)s * 0.06466165413533835f;
  float z  = (ivd - mu) * 16.27906976744186f;
  return expf(-0.5f*z*z) * cu;
}
// pack two f32 -> u32 holding two bf16 (RTNE), lo in bits 0..15
__device__ __forceinline__ unsigned bf16pack(float lo, float hi){
  unsigned ul = __float_as_uint(lo), uh = __float_as_uint(hi);
  unsigned rl = (ul + 0x7fffu + ((ul>>16)&1u)) >> 16;
  unsigned rh = (uh + 0x7fffu + ((uh>>16)&1u)) & 0xffff0000u;
  return rl | rh;
}

// ---------------- setup: geometry, sense table, encodings, W->B-frag ---------
__global__ __launch_bounds__(256) void k_setup(
    const int* __restrict__ pf, const int* __restrict__ ps,
    const int* __restrict__ species,
    const float* __restrict__ coord, const float* __restrict__ xh,
    const float* __restrict__ pw0, const float* __restrict__ pb1,
    const float* __restrict__ Wint, const float* __restrict__ Wself,
    float* __restrict__ invd, float* __restrict__ cut,
    float* __restrict__ indf, float* __restrict__ proj0,
    float* __restrict__ sv_g, bf16* __restrict__ Wmf)
{
  int tid = blockIdx.x*256 + threadIdx.x;
  if (tid < NP){
    int i = pf[tid], j = ps[tid];
    float dx = coord[i*3+0]-coord[j*3+0];
    float dy = coord[i*3+1]-coord[j*3+1];
    float dz = coord[i*3+2]-coord[j*3+2];
    float d = sqrtf(dx*dx+dy*dy+dz*dz + 1e-12f);
    float iv = 1.f/d;
    invd[tid] = iv;
    float cu = 0.f;
    if (d < 7.5f){ float c = cosf(d * 0.20943951023931953f); cu = c*c; } // pi/15
    cut[tid] = cu;
    #pragma unroll
    for(int s=0;s<20;s++) sv_g[tid*20+s] = senseval(iv, cu, s);
  }
  if (tid < NA){
    int sp = species[tid];
    float f0 = (sp==1)?1.f:0.f, f1 = (sp==8)?1.f:0.f;
    float f2=xh[tid*3+0], f3=xh[tid*3+1], f4=xh[tid*3+2];
    indf[tid*5+0]=f0; indf[tid*5+1]=f1; indf[tid*5+2]=f2; indf[tid*5+3]=f3; indf[tid*5+4]=f4;
    proj0[tid] = pb1[0] + f0*pw0[0] + f1*pw0[1] + f2*pw0[2] + f3*pw0[3] + f4*pw0[4];
  }
  if (tid < 69120){
    int j = tid & 7, l = (tid>>3) & 63, gt = (tid>>9)%5, slab = tid/2560;
    int k = slab*32 + ((l>>4)<<3) + j;
    int g = gt*16 + (l&15);
    float v = 0.f;
    if (k < 800)      v = Wint[k*80+g];
    else if (k < 840) v = Wself[(k-800)*80+g];
    Wmf[tid] = __float2bfloat16(v);
  }
}

// ---------------- f0 = hipnn(ind_f) -> c_t, h_t (unchanged, verified) --------
__global__ __launch_bounds__(256) void k_f0(
    const int* __restrict__ ps,
    const float* __restrict__ invd, const float* __restrict__ cut,
    const float* __restrict__ indf,
    const float* __restrict__ intw, const float* __restrict__ selfw,
    const float* __restrict__ selfb,
    const float* __restrict__ aw, const float* __restrict__ ab,
    float* __restrict__ ct, float* __restrict__ hout)
{
  __shared__ float xn[4][160];
  __shared__ float env[4][100];
  __shared__ float ya[4][40];
  __shared__ float yb[4][40];
  int a_loc = threadIdx.x>>6, slot = threadIdx.x&63;
  int atom = blockIdx.x*4 + a_loc;
  int p0 = atom*DEG;
  for(int idx=slot; idx<160; idx+=64){
    int k = idx/5, f = idx%5;
    int n = ps[p0+k];
    xn[a_loc][idx] = indf[n*5+f];
  }
  __syncthreads();
  for(int e=slot; e<100; e+=64){
    int s = e/5, f = e%5;
    float acc=0.f;
    for(int k=0;k<DEG;k++){
      float sv = senseval(invd[p0+k], cut[p0+k], s);
      acc += sv * xn[a_loc][k*5+f];
    }
    env[a_loc][e]=acc;
  }
  __syncthreads();
  if (slot < 40){
    int o = slot;
    float acc = selfb[o];
    #pragma unroll
    for(int f=0;f<5;f++) acc += indf[atom*5+f]*selfw[f*40+o];
    for(int e=0;e<100;e++) acc += env[a_loc][e]*intw[e*40+o];
    ya[a_loc][o] = softplusf_(acc);
  }
  __syncthreads();
  float* cur = ya[a_loc]; float* nxt = yb[a_loc];
  for(int l=0;l<3;l++){
    if (slot<40){
      int o=slot;
      float acc = ab[l*40+o];
      for(int f=0;f<40;f++) acc += cur[f]*aw[l*1600+f*40+o];
      nxt[o] = softplusf_(acc);
    }
    __syncthreads();
    float* t=cur; cur=nxt; nxt=t;
  }
  if (slot<20){
    ct[atom*20+slot]   = cur[slot];
    hout[atom*20+slot] = cur[20+slot];
  }
}

// ---------------- fused step: xt (molecule-wide) + env + MFMA + LSTM ---------
// 256 blocks x 512 threads; block owns atoms [blk*16, blk*16+16), molecule blk>>3.
__global__ __launch_bounds__(512) void k_step(
    const int* __restrict__ ps,
    const float* __restrict__ sv_g,
    const float* __restrict__ xraw, const float* __restrict__ x0_in,
    int use_raw, int col,
    const float* __restrict__ intw1, const float* __restrict__ selfw1,
    const float* __restrict__ selfb1,
    const float* __restrict__ aw1, const float* __restrict__ ab1,
    const float* __restrict__ hin,
    const bf16* __restrict__ Wmf, const float* __restrict__ Wb,
    const float* __restrict__ pw1, const float* __restrict__ proj0,
    float* __restrict__ ct, float* __restrict__ hout, float* __restrict__ x0,
    float* __restrict__ outp, int out_col)
{
  __shared__ float smem[14848];                       // 59,392 B
  float* xh_s  = smem;                                // [128][40] x|h
  float* xin_s = smem + 5120;                         // [128]
  unsigned char* nb8 = (unsigned char*)(smem + 5248); // [128][32] local idx
  float* env1  = smem + 6272;                         // [128][20] (xt phase)
  float* yA    = smem + 8832;                         // [128][20]
  float* yB    = smem + 11392;                        // [128][20]
  unsigned* env_p = (unsigned*)(smem + 6272);         // [16][436] (post-xt)
  float* tmp_s = smem + 13248;                        // [16][80]
  float* red_s = smem + 14528;                        // [16][20]

  const int t = threadIdx.x;
  const int blk = blockIdx.x;
  const int abase = blk*16;
  const int nbase = (blk>>3)*128;

  // ---- stage: xin, h-half of xh_s, neighbor local indices
  if (t < 128){
    xin_s[t] = use_raw ? xraw[(nbase+t)*2+col] : x0_in[nbase+t];
  }
  for(int i=t; i<2560; i+=512){
    int r=i/20, f=i%20;
    xh_s[r*40+20+f] = hin[(nbase+r)*20+f];
  }
  for(int i=t; i<4096; i+=512){
    nb8[i] = (unsigned char)(ps[nbase*DEG + i] - nbase);
  }
  __syncthreads();

  // ---- xt env1: env1[r][s] = sum_k sv[r,k,s] * xin[nb[r][k]]
  for(int task=t; task<2560; task+=512){
    int r=task/20, s=task%20;
    const float* svp = sv_g + (nbase+r)*640 + s;
    const unsigned char* nbr = nb8 + r*32;
    float acc=0.f;
    #pragma unroll 8
    for(int k=0;k<32;k++) acc += svp[k*20]*xin_s[nbr[k]];
    env1[r*20+s]=acc;
  }
  __syncthreads();

  // ---- xt interact layer
  for(int task=t; task<2560; task+=512){
    int r=task/20, o=task%20;
    float acc = selfb1[o] + xin_s[r]*selfw1[o];
    const float* e = env1 + r*20;
    #pragma unroll
    for(int s=0;s<20;s++) acc += e[s]*intw1[s*20+o];
    yA[r*20+o]=softplusf_(acc);
  }
  __syncthreads();

  // ---- 3 atom layers: yA->yB->yA->xh_s (x-half)
  for(int l=0;l<3;l++){
    const float* src = (l==1)? yB : yA;
    for(int task=t; task<2560; task+=512){
      int r=task/20, o=task%20;
      float acc = ab1[l*20+o];
      const float* sr = src + r*20;
      #pragma unroll
      for(int f=0;f<20;f++) acc += sr[f]*aw1[l*400+f*20+o];
      float y = softplusf_(acc);
      if (l==0)      yB[r*20+o]=y;
      else if (l==1) yA[r*20+o]=y;
      else           xh_s[r*40+o]=y;
    }
    __syncthreads();
  }

  // ---- ph1: env accumulate for own 16 atoms; thread=(a,f2), acc[s][2]
  float acc2[20][2];
  float selfp0 = 0.f, selfp1 = 0.f;
  if (t < 320){
    int a = t/20, f2 = t%20;
    int atom = abase + a;
    int a_own = (blk&7)*16 + a;
    #pragma unroll
    for(int s=0;s<20;s++){ acc2[s][0]=0.f; acc2[s][1]=0.f; }
    const float* svp = sv_g + atom*640;
    const unsigned char* nbr = nb8 + a_own*32;
    for(int k=0;k<DEG;k++){
      int nl = nbr[k];
      float2 ft = *(const float2*)(xh_s + nl*40 + f2*2);
      const float4* sq = (const float4*)(svp + k*20);
      float4 q0=sq[0], q1=sq[1], q2=sq[2], q3=sq[3], q4=sq[4];
      float svv[20] = {q0.x,q0.y,q0.z,q0.w, q1.x,q1.y,q1.z,q1.w,
                       q2.x,q2.y,q2.z,q2.w, q3.x,q3.y,q3.z,q3.w,
                       q4.x,q4.y,q4.z,q4.w};
      #pragma unroll
      for(int s=0;s<20;s++){ acc2[s][0] += svv[s]*ft.x; acc2[s][1] += svv[s]*ft.y; }
    }
    selfp0 = xh_s[a_own*40 + f2*2];
    selfp1 = xh_s[a_own*40 + f2*2 + 1];
  }
  __syncthreads();

  // ---- ph2: env_p bf16 pairs; K order k = s*40+f, self k=800+f, pad to 864
  if (t < 320){
    int a = t/20, f2 = t%20;
    unsigned* er = env_p + a*436;
    #pragma unroll
    for(int s=0;s<20;s++) er[s*20+f2] = bf16pack(acc2[s][0], acc2[s][1]);
    er[400+f2] = bf16pack(selfp0, selfp1);
    if (f2 < 12) er[420+f2] = 0u;
  }
  __syncthreads();

  // ---- ph3: MFMA GEMM, 5 waves x 16-wide g-tiles, K=864 = 27 slabs
  if (t < 320){
    int wv = t >> 6, l = t & 63;
    f32x4 cacc = {0.f,0.f,0.f,0.f};
    const unsigned* abase_p = env_p + (l & 15)*436 + ((l>>4)<<2);
    const short8v* bptr = (const short8v*)Wmf + (wv*64 + l);
    #pragma unroll 3
    for(int slab=0; slab<27; ++slab){
      short8v av = *(const short8v*)(abase_p + slab*16);
      short8v bv = bptr[slab*320];
      cacc = __builtin_amdgcn_mfma_f32_16x16x32_bf16(av, bv, cacc, 0,0,0);
    }
    int g = wv*16 + (l & 15);
    float wb = Wb[g];
    int r0 = (l>>4)*4;
    #pragma unroll
    for(int r=0;r<4;r++) tmp_s[(r0+r)*80 + g] = cacc[r] + wb;
  }
  __syncthreads();

  // ---- ph4: LSTM gates + h/c update + output projection
  if (t < 320){
    int a = t/20, u = t%20;
    int atom = abase + a;
    float4 tv = *(const float4*)(tmp_s + a*80 + u*4);
    float cold = ct[atom*20+u];
    float cnew = sigmoidf_(tv.y)*cold + sigmoidf_(tv.x)*tanhf(tv.z);
    float og   = sigmoidf_(tv.w);
    ct[atom*20+u]   = cnew;
    hout[atom*20+u] = og*tanhf(cnew);
    red_s[a*20+u]   = og*pw1[u];
  }
  __syncthreads();
  if (t < 320 && (t%20)==0){
    int a = t/20, atom = abase + a;
    float accx = proj0[atom];
    #pragma unroll
    for(int u=0;u<20;u++) accx += red_s[a*20+u];
    x0[atom] = accx;
    if(out_col>=0) outp[atom*3+out_col] = accx;
  }
}

extern "C" void kernel_launch(void* const* d_in, const int* in_sizes, int n_in,
                              void* d_out, int out_size, void* d_ws, size_t ws_size,
                              hipStream_t stream)
{
  const int*   species = (const int*)  d_in[0];
  const float* coord   = (const float*)d_in[1];
  const float* xh      = (const float*)d_in[2];
  const float* xraw    = (const float*)d_in[3];
  const int*   pf      = (const int*)  d_in[4];
  const int*   ps      = (const int*)  d_in[5];
  const float* h0_intw = (const float*)d_in[6];
  const float* h0_sw   = (const float*)d_in[7];
  const float* h0_sb   = (const float*)d_in[8];
  const float* h0_aw   = (const float*)d_in[9];
  const float* h0_ab   = (const float*)d_in[10];
  const float* h1_intw = (const float*)d_in[11];
  const float* h1_sw   = (const float*)d_in[12];
  const float* h1_sb   = (const float*)d_in[13];
  const float* h1_aw   = (const float*)d_in[14];
  const float* h1_ab   = (const float*)d_in[15];
  const float* W_intw  = (const float*)d_in[16];
  const float* W_sw    = (const float*)d_in[17];
  const float* W_sb    = (const float*)d_in[18];
  const float* pw0     = (const float*)d_in[19];
  const float* pw1     = (const float*)d_in[20];
  const float* pb1     = (const float*)d_in[21];
  float* outp = (float*)d_out;

  float* w = (float*)d_ws;
  float* invd = w;  w += NP;
  float* cut  = w;  w += NP;
  float* indf = w;  w += NA*5;
  float* proj0= w;  w += NA;
  float* hA   = w;  w += NA*20;
  float* hB   = w;  w += NA*20;
  float* ct   = w;  w += NA*20;
  float* x0   = w;  w += NA;
  float* sv_g = w;  w += NP*20;
  bf16*  Wmf  = (bf16*)w;              // 69120 bf16

  k_setup<<<512,256,0,stream>>>(pf,ps,species,coord,xh,pw0,pb1,W_intw,W_sw,
                                invd,cut,indf,proj0,sv_g,Wmf);
  k_f0<<<1024,256,0,stream>>>(ps,invd,cut,indf,h0_intw,h0_sw,h0_sb,h0_aw,h0_ab,
                              ct,hA);

  const float* hin = hA; float* ho = hB;
  for(int step=0; step<5; ++step){
    int use_raw = (step<2)?1:0;
    int col = (step<2)? step : 0;
    int out_col = (step>=2)? (step-2) : -1;
    k_step<<<256,512,0,stream>>>(ps, sv_g, xraw, x0, use_raw, col,
                                 h1_intw, h1_sw, h1_sb, h1_aw, h1_ab,
                                 hin, Wmf, W_sb, pw1, proj0,
                                 ct, ho, x0, outp, out_col);
    const float* tswap = hin; hin = ho; ho = (float*)tswap;
  }
}

// Round 6
// 219.653 us; speedup vs baseline: 1.1306x; 1.1306x over previous
//
#include <hip/hip_runtime.h>
#include <hip/hip_bf16.h>

// Round 6: fused k_step without sv_g table (48MB/dispatch HBM fetch was the
// round-5 regression). senseval recomputed from LDS-staged ivcu (float2).
// Per-atom env (20x32)x(32x40) now via MFMA with A-fragments built directly
// from senseval in registers; D packed to the K=864 GEMM A-buffer via
// shfl_xor pairing. Fragment layouts identical to round-4-verified GEMM.
// 7 launches: setup, f0, 5 x k_step.

#define DEG 32
#define NA 4096
#define NP 131072

typedef __hip_bfloat16 bf16;
typedef __attribute__((ext_vector_type(8))) short short8v;
typedef __attribute__((ext_vector_type(4))) float f32x4;

// ---- LDS float offsets (64,768 B total) ----
#define OFF_XIN  0        // [128]                 whole kernel
#define OFF_NB   128      // u8[4096]              whole kernel
#define OFF_IVCU 1152     // float2[4096] = 8192f  phases 0-1
#define OFF_XH   1152     // [128][40] = 5120f     phase 2+ (x|h)
#define OFF_ER   6272     // u32[16*436] = 6976    phase 6+ (A operand K=864)
#define OFF_ENV1 9344     // [128][20] = 2560      phase 1-2
#define OFF_YB   9344     // [128][20]             layers (reuse env1)
#define OFF_YA   11904    // [128][20] = 2560
#define OFF_TMP  13248    // [16][80] = 1280       phase 7+
#define OFF_WTS  14464    // 1700f                 phases 0-5 (xt weights)
#define OFF_RED  14528    // [16][20] = 320        phase 8 (over dead wts)
#define SMEM_F   16192

__device__ __forceinline__ float sigmoidf_(float x){ return 1.f/(1.f+expf(-x)); }
__device__ __forceinline__ float softplusf_(float x){ return fmaxf(x,0.f) + log1pf(expf(-fabsf(x))); }
// mu_s = linspace(1/5, 1/0.7, 20); sigma = (1/0.7-1/5)/20
__device__ __forceinline__ float senseval(float ivd, float cu, int s){
  float mu = 0.2f + (float)s * 0.06466165413533835f;
  float z  = (ivd - mu) * 16.27906976744186f;
  return expf(-0.5f*z*z) * cu;
}
__device__ __forceinline__ unsigned bf16pack(float lo, float hi){
  unsigned ul = __float_as_uint(lo), uh = __float_as_uint(hi);
  unsigned rl = (ul + 0x7fffu + ((ul>>16)&1u)) >> 16;
  unsigned rh = (uh + 0x7fffu + ((uh>>16)&1u)) & 0xffff0000u;
  return rl | rh;
}
union UU { unsigned u[4]; short8v v; };

// write one 16x16 D-tile (rows s<20, cols f<40) into er bf16-pair buffer
__device__ __forceinline__ void wr_tile(unsigned* er, f32x4 D, int M, int N,
                                        int lg, int lr, int l){
  #pragma unroll
  for(int r=0;r<4;r++){
    float vd = D[r];
    float pr = __shfl_xor(vd, 1);
    int s = M*16 + lg*4 + r, f = N*16 + lr;
    if(!(l&1) && s<20 && f<40) er[s*20 + (f>>1)] = bf16pack(vd, pr);
  }
}

// ---------------- setup: geometry(float2 ivcu), encodings, W->B-frag ---------
__global__ __launch_bounds__(256) void k_setup(
    const int* __restrict__ pf, const int* __restrict__ ps,
    const int* __restrict__ species,
    const float* __restrict__ coord, const float* __restrict__ xh,
    const float* __restrict__ pw0, const float* __restrict__ pb1,
    const float* __restrict__ Wint, const float* __restrict__ Wself,
    float2* __restrict__ ivcu_g,
    float* __restrict__ indf, float* __restrict__ proj0,
    bf16* __restrict__ Wmf)
{
  int tid = blockIdx.x*256 + threadIdx.x;
  if (tid < NP){
    int i = pf[tid], j = ps[tid];
    float dx = coord[i*3+0]-coord[j*3+0];
    float dy = coord[i*3+1]-coord[j*3+1];
    float dz = coord[i*3+2]-coord[j*3+2];
    float d = sqrtf(dx*dx+dy*dy+dz*dz + 1e-12f);
    float cu = 0.f;
    if (d < 7.5f){ float c = cosf(d * 0.20943951023931953f); cu = c*c; } // pi/15
    ivcu_g[tid] = make_float2(1.f/d, cu);
  }
  if (tid < NA){
    int sp = species[tid];
    float f0 = (sp==1)?1.f:0.f, f1 = (sp==8)?1.f:0.f;
    float f2=xh[tid*3+0], f3=xh[tid*3+1], f4=xh[tid*3+2];
    indf[tid*5+0]=f0; indf[tid*5+1]=f1; indf[tid*5+2]=f2; indf[tid*5+3]=f3; indf[tid*5+4]=f4;
    proj0[tid] = pb1[0] + f0*pw0[0] + f1*pw0[1] + f2*pw0[2] + f3*pw0[3] + f4*pw0[4];
  }
  if (tid < 69120){
    int j = tid & 7, l = (tid>>3) & 63, gt = (tid>>9)%5, slab = tid/2560;
    int k = slab*32 + ((l>>4)<<3) + j;
    int g = gt*16 + (l&15);
    float v = 0.f;
    if (k < 800)      v = Wint[k*80+g];
    else if (k < 840) v = Wself[(k-800)*80+g];
    Wmf[tid] = __float2bfloat16(v);
  }
}

// ---------------- f0 = hipnn(ind_f) -> c_t, h_t ------------------------------
__global__ __launch_bounds__(256) void k_f0(
    const int* __restrict__ ps,
    const float2* __restrict__ ivcu_g,
    const float* __restrict__ indf,
    const float* __restrict__ intw, const float* __restrict__ selfw,
    const float* __restrict__ selfb,
    const float* __restrict__ aw, const float* __restrict__ ab,
    float* __restrict__ ct, float* __restrict__ hout)
{
  __shared__ float xn[4][160];
  __shared__ float env[4][100];
  __shared__ float ya[4][40];
  __shared__ float yb[4][40];
  int a_loc = threadIdx.x>>6, slot = threadIdx.x&63;
  int atom = blockIdx.x*4 + a_loc;
  int p0 = atom*DEG;
  for(int idx=slot; idx<160; idx+=64){
    int k = idx/5, f = idx%5;
    int n = ps[p0+k];
    xn[a_loc][idx] = indf[n*5+f];
  }
  __syncthreads();
  for(int e=slot; e<100; e+=64){
    int s = e/5, f = e%5;
    float acc=0.f;
    for(int k=0;k<DEG;k++){
      float2 vc = ivcu_g[p0+k];
      acc += senseval(vc.x, vc.y, s) * xn[a_loc][k*5+f];
    }
    env[a_loc][e]=acc;
  }
  __syncthreads();
  if (slot < 40){
    int o = slot;
    float acc = selfb[o];
    #pragma unroll
    for(int f=0;f<5;f++) acc += indf[atom*5+f]*selfw[f*40+o];
    for(int e=0;e<100;e++) acc += env[a_loc][e]*intw[e*40+o];
    ya[a_loc][o] = softplusf_(acc);
  }
  __syncthreads();
  float* cur = ya[a_loc]; float* nxt = yb[a_loc];
  for(int l=0;l<3;l++){
    if (slot<40){
      int o=slot;
      float acc = ab[l*40+o];
      for(int f=0;f<40;f++) acc += cur[f]*aw[l*1600+f*40+o];
      nxt[o] = softplusf_(acc);
    }
    __syncthreads();
    float* t=cur; cur=nxt; nxt=t;
  }
  if (slot<20){
    ct[atom*20+slot]   = cur[slot];
    hout[atom*20+slot] = cur[20+slot];
  }
}

// ---------------- fused step -------------------------------------------------
__global__ __launch_bounds__(512) void k_step(
    const int* __restrict__ ps,
    const float2* __restrict__ ivcu_g,
    const float* __restrict__ xraw, const float* __restrict__ x0_in,
    int use_raw, int col,
    const float* __restrict__ intw1, const float* __restrict__ selfw1,
    const float* __restrict__ selfb1,
    const float* __restrict__ aw1, const float* __restrict__ ab1,
    const float* __restrict__ hin,
    const bf16* __restrict__ Wmf, const float* __restrict__ Wb,
    const float* __restrict__ pw1, const float* __restrict__ proj0,
    float* __restrict__ ct, float* __restrict__ hout, float* __restrict__ x0,
    float* __restrict__ outp, int out_col)
{
  __shared__ float smem[SMEM_F];
  float* xin_s = smem + OFF_XIN;
  unsigned char* nb8u = (unsigned char*)(smem + OFF_NB);
  float* xh_s  = smem + OFF_XH;
  float* env1  = smem + OFF_ENV1;
  float* yA    = smem + OFF_YA;
  float* yB    = smem + OFF_YB;
  unsigned* env_p = (unsigned*)(smem + OFF_ER);
  float* tmp_s = smem + OFF_TMP;
  float* red_s = smem + OFF_RED;
  float* wts   = smem + OFF_WTS;

  const int t = threadIdx.x;
  const int blk = blockIdx.x;
  const int abase = blk*16;
  const int nbase = (blk>>3)*128;

  // ---- ph0: stage xin, ivcu, nb8, transposed xt weights
  if (t < 128) xin_s[t] = use_raw ? xraw[(nbase+t)*2+col] : x0_in[nbase+t];
  {
    float2* iv_l = (float2*)(smem + OFF_IVCU);
    for(int i=t;i<4096;i+=512){
      iv_l[i] = ivcu_g[nbase*DEG + i];
      nb8u[i] = (unsigned char)(ps[nbase*DEG + i] - nbase);
    }
  }
  for(int i=t;i<1700;i+=512){
    float v;
    if(i<400){ int o=i/20, s=i%20; v=intw1[s*20+o]; }
    else if(i<420) v=selfw1[i-400];
    else if(i<440) v=selfb1[i-420];
    else if(i<1640){ int q=i-440; int l=q/400, rem=q%400, o=rem/20, f=rem%20;
                     v=aw1[l*400+f*20+o]; }
    else v=ab1[i-1640];
    wts[i]=v;
  }
  __syncthreads();

  // ---- ph1: xt env1[r][s]; thread=(r, s0), 5 s per thread, 1 pair-load per k
  {
    int r = t&127, s0 = t>>7;
    const float2* ivr = (const float2*)(smem + OFF_IVCU) + r*32;
    const unsigned char* nbr = nb8u + r*32;
    float acc[5]={0.f,0.f,0.f,0.f,0.f};
    for(int k=0;k<32;k++){
      float2 vc = ivr[k];
      float xv = xin_s[nbr[k]];
      #pragma unroll
      for(int i=0;i<5;i++) acc[i] += senseval(vc.x, vc.y, s0+4*i)*xv;
    }
    #pragma unroll
    for(int i=0;i<5;i++) env1[r*20 + s0+4*i] = acc[i];
  }
  __syncthreads();

  // ---- ph2: h-stage into xh_s (ivcu dead) + xt interact layer
  for(int i=t;i<2560;i+=512){
    int r=i/20, f=i%20;
    xh_s[r*40+20+f] = hin[(nbase+r)*20+f];
  }
  {
    int r=t&127, o0=t>>7;
    float e[20];
    { const float4* e4=(const float4*)(env1 + r*20);
      #pragma unroll
      for(int q=0;q<5;q++){ float4 x=e4[q]; e[4*q]=x.x; e[4*q+1]=x.y; e[4*q+2]=x.z; e[4*q+3]=x.w; } }
    float xr_=xin_s[r];
    #pragma unroll
    for(int i=0;i<5;i++){
      int o=o0+4*i;
      const float4* w4=(const float4*)(wts + o*20);
      float acc = wts[420+o] + xr_*wts[400+o];
      #pragma unroll
      for(int q=0;q<5;q++){ float4 w=w4[q];
        acc += e[4*q]*w.x + e[4*q+1]*w.y + e[4*q+2]*w.z + e[4*q+3]*w.w; }
      yA[r*20+o]=softplusf_(acc);
    }
  }
  __syncthreads();

  // ---- ph3-5: three atom layers (yA->yB->yA->xh_s x-half)
  #pragma unroll
  for(int L=0;L<3;L++){
    const float* src = (L==1)? yB : yA;
    int r=t&127, o0=t>>7;
    float e[20];
    { const float4* e4=(const float4*)(src + r*20);
      #pragma unroll
      for(int q=0;q<5;q++){ float4 x=e4[q]; e[4*q]=x.x; e[4*q+1]=x.y; e[4*q+2]=x.z; e[4*q+3]=x.w; } }
    #pragma unroll
    for(int i=0;i<5;i++){
      int o=o0+4*i;
      const float4* w4=(const float4*)(wts + 440 + L*400 + o*20);
      float acc = wts[1640 + L*20 + o];
      #pragma unroll
      for(int q=0;q<5;q++){ float4 w=w4[q];
        acc += e[4*q]*w.x + e[4*q+1]*w.y + e[4*q+2]*w.z + e[4*q+3]*w.w; }
      float y = softplusf_(acc);
      if (L==0)      yB[r*20+o]=y;
      else if (L==1) yA[r*20+o]=y;
      else           xh_s[r*40+o]=y;
    }
    __syncthreads();
  }

  // ---- ph6: per-atom env via MFMA -> er (A operand of K=864 GEMM)
  {
    int wv = t>>6, l = t&63;
    int lg = l>>4, lr = l&15;
    f32x4 z = {0.f,0.f,0.f,0.f};
    #pragma unroll
    for(int ai=0; ai<2; ++ai){
      int a = wv*2 + ai;
      int a_own = (blk&7)*16 + a;
      int atom_g = abase + a;
      // A fragments: sv(s, k) built in-register
      const float4* ivp = (const float4*)(ivcu_g + atom_g*32 + lg*8);
      float4 p0=ivp[0], p1=ivp[1], p2=ivp[2], p3=ivp[3];
      float ivv[8]={p0.x,p0.z,p1.x,p1.z,p2.x,p2.z,p3.x,p3.z};
      float cuv[8]={p0.y,p0.w,p1.y,p1.w,p2.y,p2.w,p3.y,p3.w};
      UU A0, A1;
      int s1 = 16+lr;
      #pragma unroll
      for(int q=0;q<4;q++){
        A0.u[q] = bf16pack(senseval(ivv[2*q],cuv[2*q],lr),
                           senseval(ivv[2*q+1],cuv[2*q+1],lr));
        float u0=0.f, u1=0.f;
        if (s1<20){ u0=senseval(ivv[2*q],cuv[2*q],s1);
                    u1=senseval(ivv[2*q+1],cuv[2*q+1],s1); }
        A1.u[q] = bf16pack(u0,u1);
      }
      // neighbor local indices for this lane's k-chunk
      const unsigned* nbw = (const unsigned*)(nb8u + a_own*32 + lg*8);
      unsigned nw0=nbw[0], nw1=nbw[1];
      int nl[8];
      #pragma unroll
      for(int j=0;j<4;j++){ nl[j]=(nw0>>(8*j))&255; nl[4+j]=(nw1>>(8*j))&255; }
      // B fragments (gathered neighbor features) + MFMA
      f32x4 d00,d01,d02,d10,d11,d12;
      { UU B; int f=lr;
        #pragma unroll
        for(int q=0;q<4;q++)
          B.u[q]=bf16pack(xh_s[nl[2*q]*40+f], xh_s[nl[2*q+1]*40+f]);
        d00=__builtin_amdgcn_mfma_f32_16x16x32_bf16(A0.v,B.v,z,0,0,0);
        d10=__builtin_amdgcn_mfma_f32_16x16x32_bf16(A1.v,B.v,z,0,0,0); }
      { UU B; int f=16+lr;
        #pragma unroll
        for(int q=0;q<4;q++)
          B.u[q]=bf16pack(xh_s[nl[2*q]*40+f], xh_s[nl[2*q+1]*40+f]);
        d01=__builtin_amdgcn_mfma_f32_16x16x32_bf16(A0.v,B.v,z,0,0,0);
        d11=__builtin_amdgcn_mfma_f32_16x16x32_bf16(A1.v,B.v,z,0,0,0); }
      { UU B; int f=32+lr; int val=(f<40);
        #pragma unroll
        for(int q=0;q<4;q++)
          B.u[q]= val ? bf16pack(xh_s[nl[2*q]*40+f], xh_s[nl[2*q+1]*40+f]) : 0u;
        d02=__builtin_amdgcn_mfma_f32_16x16x32_bf16(A0.v,B.v,z,0,0,0);
        d12=__builtin_amdgcn_mfma_f32_16x16x32_bf16(A1.v,B.v,z,0,0,0); }
      unsigned* er = env_p + a*436;
      wr_tile(er,d00,0,0,lg,lr,l); wr_tile(er,d01,0,1,lg,lr,l);
      wr_tile(er,d02,0,2,lg,lr,l); wr_tile(er,d10,1,0,lg,lr,l);
      wr_tile(er,d11,1,1,lg,lr,l); wr_tile(er,d12,1,2,lg,lr,l);
    }
    // self rows (k=800+f) and zero pad (k=840..863)
    if (t<320){ int a=t/20, f2=t%20; int a_own=(blk&7)*16+a;
      env_p[a*436+400+f2]=bf16pack(xh_s[a_own*40+2*f2], xh_s[a_own*40+2*f2+1]); }
    if (t<256){ env_p[(t>>4)*436+420+(t&15)]=0u; }
  }
  __syncthreads();

  // ---- ph7: MFMA GEMM K=864, 5 waves x 16-wide g-tiles (verified r4/r5)
  if (t < 320){
    int wv = t >> 6, l = t & 63;
    f32x4 cacc = {0.f,0.f,0.f,0.f};
    const unsigned* abase_p = env_p + (l & 15)*436 + ((l>>4)<<2);
    const short8v* bptr = (const short8v*)Wmf + (wv*64 + l);
    #pragma unroll 3
    for(int slab=0; slab<27; ++slab){
      short8v av = *(const short8v*)(abase_p + slab*16);
      short8v bv = bptr[slab*320];
      cacc = __builtin_amdgcn_mfma_f32_16x16x32_bf16(av, bv, cacc, 0,0,0);
    }
    int g = wv*16 + (l & 15);
    float wb = Wb[g];
    int r0 = (l>>4)*4;
    #pragma unroll
    for(int r=0;r<4;r++) tmp_s[(r0+r)*80 + g] = cacc[r] + wb;
  }
  __syncthreads();

  // ---- ph8: LSTM gates + h/c update + projection pieces
  if (t < 320){
    int a = t/20, u = t%20;
    int atom = abase + a;
    float4 tv = *(const float4*)(tmp_s + a*80 + u*4);
    float cold = ct[atom*20+u];
    float cnew = sigmoidf_(tv.y)*cold + sigmoidf_(tv.x)*tanhf(tv.z);
    float og   = sigmoidf_(tv.w);
    ct[atom*20+u]   = cnew;
    hout[atom*20+u] = og*tanhf(cnew);
    red_s[a*20+u]   = og*pw1[u];
  }
  __syncthreads();
  if (t < 320 && (t%20)==0){
    int a = t/20, atom = abase + a;
    float accx = proj0[atom];
    #pragma unroll
    for(int u=0;u<20;u++) accx += red_s[a*20+u];
    x0[atom] = accx;
    if(out_col>=0) outp[atom*3+out_col] = accx;
  }
}

extern "C" void kernel_launch(void* const* d_in, const int* in_sizes, int n_in,
                              void* d_out, int out_size, void* d_ws, size_t ws_size,
                              hipStream_t stream)
{
  const int*   species = (const int*)  d_in[0];
  const float* coord   = (const float*)d_in[1];
  const float* xh      = (const float*)d_in[2];
  const float* xraw    = (const float*)d_in[3];
  const int*   pf      = (const int*)  d_in[4];
  const int*   ps      = (const int*)  d_in[5];
  const float* h0_intw = (const float*)d_in[6];
  const float* h0_sw   = (const float*)d_in[7];
  const float* h0_sb   = (const float*)d_in[8];
  const float* h0_aw   = (const float*)d_in[9];
  const float* h0_ab   = (const float*)d_in[10];
  const float* h1_intw = (const float*)d_in[11];
  const float* h1_sw   = (const float*)d_in[12];
  const float* h1_sb   = (const float*)d_in[13];
  const float* h1_aw   = (const float*)d_in[14];
  const float* h1_ab   = (const float*)d_in[15];
  const float* W_intw  = (const float*)d_in[16];
  const float* W_sw    = (const float*)d_in[17];
  const float* W_sb    = (const float*)d_in[18];
  const float* pw0     = (const float*)d_in[19];
  const float* pw1     = (const float*)d_in[20];
  const float* pb1     = (const float*)d_in[21];
  float* outp = (float*)d_out;

  float* w = (float*)d_ws;
  float2* ivcu_g = (float2*)w;  w += 2*NP;
  float* indf = w;  w += NA*5;
  float* proj0= w;  w += NA;
  float* hA   = w;  w += NA*20;
  float* hB   = w;  w += NA*20;
  float* ct   = w;  w += NA*20;
  float* x0   = w;  w += NA;
  bf16*  Wmf  = (bf16*)w;              // 69120 bf16

  k_setup<<<512,256,0,stream>>>(pf,ps,species,coord,xh,pw0,pb1,W_intw,W_sw,
                                ivcu_g,indf,proj0,Wmf);
  k_f0<<<1024,256,0,stream>>>(ps,ivcu_g,indf,h0_intw,h0_sw,h0_sb,h0_aw,h0_ab,
                              ct,hA);

  const float* hin = hA; float* ho = hB;
  for(int step=0; step<5; ++step){
    int use_raw = (step<2)?1:0;
    int col = (step<2)? step : 0;
    int out_col = (step>=2)? (step-2) : -1;
    k_step<<<256,512,0,stream>>>(ps, ivcu_g, xraw, x0, use_raw, col,
                                 h1_intw, h1_sw, h1_sb, h1_aw, h1_ab,
                                 hin, Wmf, W_sb, pw1, proj0,
                                 ct, ho, x0, outp, out_col);
    const float* tswap = hin; hin = ho; ho = (float*)tswap;
  }
}

// Round 7
// 134.491 us; speedup vs baseline: 1.8465x; 1.6332x over previous
//
#include <hip/hip_runtime.h>
#include <hip/hip_bf16.h>

// Round 7: fast-transcendental + conflict-free fused k_step.
//  - __expf/__logf/rcp based sense/softplus/sigmoid/tanh (v_exp_f32, not libm).
//  - env: (atom,f2) f32 accum; X as bf16 pairs in LDS (xhp), sv f32 tile in
//    LDS (stride 652, 2-way max); no random scalar gathers, no shfl.
//  - LDS arena overlays {wts,env1,yA} -> sv -> er; 61.7KB static.
//  - XCD swizzle: 8 sibling blocks of a molecule -> same XCD (mol=blk&31).
//  - x0 double-buffered (fixes same-dispatch read/write race).
// 7 launches: setup, f0, 5 x k_step.

#define DEG 32
#define NA 4096
#define NP 131072

typedef __hip_bfloat16 bf16;
typedef __attribute__((ext_vector_type(8))) short short8v;
typedef __attribute__((ext_vector_type(4))) float f32x4;

// ---- fast math (abs err ~1e-6, irrelevant vs bf16 4e-3 rounding) ----
__device__ __forceinline__ float frcp(float x){ return __builtin_amdgcn_rcpf(x); }
__device__ __forceinline__ float sigmoid_f(float x){ return frcp(1.f + __expf(-x)); }
__device__ __forceinline__ float tanh_f(float x){ return 1.f - 2.f*frcp(__expf(2.f*x)+1.f); }
__device__ __forceinline__ float softplus_f(float x){ return fmaxf(x,0.f) + __logf(1.f + __expf(-fabsf(x))); }
// z0=(1/d - 0.2)*16.279...; z_s = z0 - s*(20/19); sense = cut*exp(-0.5 z^2)
#define Z0F 16.27906976744186f
#define DZ  1.0526315789473684f
__device__ __forceinline__ unsigned bf16pack(float lo, float hi){
  unsigned ul = __float_as_uint(lo), uh = __float_as_uint(hi);
  unsigned rl = (ul + 0x7fffu + ((ul>>16)&1u)) >> 16;
  unsigned rh = (uh + 0x7fffu + ((uh>>16)&1u)) & 0xffff0000u;
  return rl | rh;
}

// ---------------- setup: geometry(float2 ivcu), encodings, W->B-frag ---------
__global__ __launch_bounds__(256) void k_setup(
    const int* __restrict__ pf, const int* __restrict__ ps,
    const int* __restrict__ species,
    const float* __restrict__ coord, const float* __restrict__ xh,
    const float* __restrict__ pw0, const float* __restrict__ pb1,
    const float* __restrict__ Wint, const float* __restrict__ Wself,
    float2* __restrict__ ivcu_g,
    float* __restrict__ indf, float* __restrict__ proj0,
    bf16* __restrict__ Wmf)
{
  int tid = blockIdx.x*256 + threadIdx.x;
  if (tid < NP){
    int i = pf[tid], j = ps[tid];
    float dx = coord[i*3+0]-coord[j*3+0];
    float dy = coord[i*3+1]-coord[j*3+1];
    float dz = coord[i*3+2]-coord[j*3+2];
    float d = sqrtf(dx*dx+dy*dy+dz*dz + 1e-12f);
    float cu = 0.f;
    if (d < 7.5f){ float c = __cosf(d * 0.20943951023931953f); cu = c*c; } // pi/15
    ivcu_g[tid] = make_float2(1.f/d, cu);
  }
  if (tid < NA){
    int sp = species[tid];
    float f0 = (sp==1)?1.f:0.f, f1 = (sp==8)?1.f:0.f;
    float f2=xh[tid*3+0], f3=xh[tid*3+1], f4=xh[tid*3+2];
    indf[tid*5+0]=f0; indf[tid*5+1]=f1; indf[tid*5+2]=f2; indf[tid*5+3]=f3; indf[tid*5+4]=f4;
    proj0[tid] = pb1[0] + f0*pw0[0] + f1*pw0[1] + f2*pw0[2] + f3*pw0[3] + f4*pw0[4];
  }
  if (tid < 69120){
    int j = tid & 7, l = (tid>>3) & 63, gt = (tid>>9)%5, slab = tid/2560;
    int k = slab*32 + ((l>>4)<<3) + j;
    int g = gt*16 + (l&15);
    float v = 0.f;
    if (k < 800)      v = Wint[k*80+g];
    else if (k < 840) v = Wself[(k-800)*80+g];
    Wmf[tid] = __float2bfloat16(v);
  }
}

// ---------------- f0 = hipnn(ind_f) -> c_t, h_t (fast-math swap only) --------
__global__ __launch_bounds__(256) void k_f0(
    const int* __restrict__ ps,
    const float2* __restrict__ ivcu_g,
    const float* __restrict__ indf,
    const float* __restrict__ intw, const float* __restrict__ selfw,
    const float* __restrict__ selfb,
    const float* __restrict__ aw, const float* __restrict__ ab,
    float* __restrict__ ct, float* __restrict__ hout)
{
  __shared__ float xn[4][160];
  __shared__ float env[4][100];
  __shared__ float ya[4][40];
  __shared__ float yb[4][40];
  int a_loc = threadIdx.x>>6, slot = threadIdx.x&63;
  int atom = blockIdx.x*4 + a_loc;
  int p0 = atom*DEG;
  for(int idx=slot; idx<160; idx+=64){
    int k = idx/5, f = idx%5;
    int n = ps[p0+k];
    xn[a_loc][idx] = indf[n*5+f];
  }
  __syncthreads();
  for(int e=slot; e<100; e+=64){
    int s = e/5, f = e%5;
    float sz = (float)s*DZ;
    float acc=0.f;
    for(int k=0;k<DEG;k++){
      float2 vc = ivcu_g[p0+k];
      float z = (vc.x-0.2f)*Z0F - sz;
      acc += vc.y*__expf(-0.5f*z*z) * xn[a_loc][k*5+f];
    }
    env[a_loc][e]=acc;
  }
  __syncthreads();
  if (slot < 40){
    int o = slot;
    float acc = selfb[o];
    #pragma unroll
    for(int f=0;f<5;f++) acc += indf[atom*5+f]*selfw[f*40+o];
    for(int e=0;e<100;e++) acc += env[a_loc][e]*intw[e*40+o];
    ya[a_loc][o] = softplus_f(acc);
  }
  __syncthreads();
  float* cur = ya[a_loc]; float* nxt = yb[a_loc];
  for(int l=0;l<3;l++){
    if (slot<40){
      int o=slot;
      float acc = ab[l*40+o];
      for(int f=0;f<40;f++) acc += cur[f]*aw[l*1600+f*40+o];
      nxt[o] = softplus_f(acc);
    }
    __syncthreads();
    float* t=cur; cur=nxt; nxt=t;
  }
  if (slot<20){
    ct[atom*20+slot]   = cur[slot];
    hout[atom*20+slot] = cur[20+slot];
  }
}

// ---- LDS word offsets (61,696 B) ----
#define A_XIN 0        // [128]
#define A_NB  128      // u8[4096] = 1024 w
#define A_XHP 1152     // u32[128*20] = 2560 w (bf16 pairs x|h)
#define A_AR  3712     // arena 10432 w
#define A_WTS 3712     //   ph0-5: wts 1700
#define A_EV1 5412     //   ph1-5: env1/yB 2560
#define A_YA  7972     //   ph2-5: yA 2560
#define A_SV  3712     //   ph sv..env: sv[16][652] = 10432
#define A_ER  3712     //   ph pack..gemm: er u32[16*436] = 6976
#define A_RED 10688    //   ph lstm: red 320
#define A_TMP 14144    // tmp [16][80] = 1280
#define SMEMW 15424

// ---------------- fused step --------------------------------------------------
__global__ __launch_bounds__(512) void k_step(
    const int* __restrict__ ps,
    const float2* __restrict__ ivcu,
    const float* __restrict__ xraw, const float* __restrict__ x0_in,
    int use_raw, int col,
    const float* __restrict__ intw1, const float* __restrict__ selfw1,
    const float* __restrict__ selfb1,
    const float* __restrict__ aw1, const float* __restrict__ ab1,
    const float* __restrict__ hin,
    const bf16* __restrict__ Wmf, const float* __restrict__ Wb,
    const float* __restrict__ pw1, const float* __restrict__ proj0,
    float* __restrict__ ct, float* __restrict__ hout, float* __restrict__ x0,
    float* __restrict__ outp, int out_col)
{
  __shared__ float smem[SMEMW];
  const int t = threadIdx.x;
  const int d = blockIdx.x;
  const int mol = d & 31, j = d >> 5;      // siblings of a molecule share XCD
  const int nbase = mol*128;
  const int abase = nbase + j*16;

  float* xin_s = smem + A_XIN;
  unsigned char* nb8 = (unsigned char*)(smem + A_NB);
  unsigned* xhp = (unsigned*)(smem + A_XHP);
  float* wts  = smem + A_WTS;
  float* env1 = smem + A_EV1;
  float* yA   = smem + A_YA;
  float* sv_s = smem + A_SV;
  unsigned* er = (unsigned*)(smem + A_ER);
  float* red_s = smem + A_RED;
  float* tmp_s = smem + A_TMP;

  // ---- ph0: stage xin, nb8, transposed xt weights
  if (t < 128) xin_s[t] = use_raw ? xraw[(nbase+t)*2+col] : x0_in[nbase+t];
  for(int i=t;i<4096;i+=512) nb8[i] = (unsigned char)(ps[nbase*DEG + i] - nbase);
  for(int i=t;i<1700;i+=512){
    float v;
    if(i<400){ int o=i/20,s=i%20; v=intw1[s*20+o]; }
    else if(i<420) v=selfw1[i-400];
    else if(i<440) v=selfb1[i-420];
    else if(i<1640){ int q=i-440,l=q/400,rem=q%400,o=rem/20,f=rem%20; v=aw1[l*400+f*20+o]; }
    else v=ab1[i-1640];
    wts[i]=v;
  }
  __syncthreads();

  // ---- ph1: xt-env for all 128 molecule atoms; thread=(r,s0), 5 s each
  {
    int r = t & 127, s0 = t >> 7;
    const float2* ivr = ivcu + (nbase + r)*DEG;
    const unsigned char* nbr = nb8 + r*32;
    float acc[5] = {0.f,0.f,0.f,0.f,0.f};
    for(int k=0;k<32;k++){
      float2 vc = ivr[k];
      float xv = xin_s[nbr[k]] * vc.y;                 // fold cut
      float z0 = (vc.x-0.2f)*Z0F - (float)s0*DZ;
      #pragma unroll
      for(int i=0;i<5;i++){
        float z = z0 - (float)(4*i)*DZ;
        acc[i] += __expf(-0.5f*z*z) * xv;
      }
    }
    #pragma unroll
    for(int i=0;i<5;i++) env1[r*20 + s0 + 4*i] = acc[i];
  }
  __syncthreads();

  // ---- ph2: h-staging (bf16 pairs) + xt interact (env1 -> yA)
  for(int i=t;i<1280;i+=512){
    int r=i/10, p=i%10;
    float2 hv = *(const float2*)(hin + (nbase+r)*20 + 2*p);
    xhp[r*20 + 10 + p] = bf16pack(hv.x, hv.y);
  }
  {
    int r = t&127, o0 = t>>7;
    float e[20];
    { const float4* e4=(const float4*)(env1 + r*20);
      float4 q0=e4[0],q1=e4[1],q2=e4[2],q3=e4[3],q4=e4[4];
      e[0]=q0.x;e[1]=q0.y;e[2]=q0.z;e[3]=q0.w; e[4]=q1.x;e[5]=q1.y;e[6]=q1.z;e[7]=q1.w;
      e[8]=q2.x;e[9]=q2.y;e[10]=q2.z;e[11]=q2.w; e[12]=q3.x;e[13]=q3.y;e[14]=q3.z;e[15]=q3.w;
      e[16]=q4.x;e[17]=q4.y;e[18]=q4.z;e[19]=q4.w; }
    float xr_ = xin_s[r];
    #pragma unroll
    for(int i=0;i<5;i++){
      int o = o0 + 4*i;
      const float* w = wts + o*20;
      float acc = wts[420+o] + xr_*wts[400+o];
      #pragma unroll
      for(int f=0;f<20;f++) acc += e[f]*w[f];
      yA[r*20+o] = softplus_f(acc);
    }
  }
  __syncthreads();

  // ---- ph3-4: layers L0 (yA->env1), L1 (env1->yA)
  #pragma unroll
  for(int L=0;L<2;L++){
    const float* src = (L==0)? yA : env1;
    float* dst       = (L==0)? env1 : yA;
    int r = t&127, o0 = t>>7;
    float e[20];
    { const float4* e4=(const float4*)(src + r*20);
      float4 q0=e4[0],q1=e4[1],q2=e4[2],q3=e4[3],q4=e4[4];
      e[0]=q0.x;e[1]=q0.y;e[2]=q0.z;e[3]=q0.w; e[4]=q1.x;e[5]=q1.y;e[6]=q1.z;e[7]=q1.w;
      e[8]=q2.x;e[9]=q2.y;e[10]=q2.z;e[11]=q2.w; e[12]=q3.x;e[13]=q3.y;e[14]=q3.z;e[15]=q3.w;
      e[16]=q4.x;e[17]=q4.y;e[18]=q4.z;e[19]=q4.w; }
    #pragma unroll
    for(int i=0;i<5;i++){
      int o = o0 + 4*i;
      const float* w = wts + 440 + L*400 + o*20;
      float acc = wts[1640 + L*20 + o];
      #pragma unroll
      for(int f=0;f<20;f++) acc += e[f]*w[f];
      dst[r*20+o] = softplus_f(acc);
    }
    __syncthreads();
  }

  // ---- ph5: layer L2 (yA -> xhp x-half, bf16 pairs)
  for(int i=t;i<1280;i+=512){
    int r=i/10, p=i%10;
    float e[20];
    { const float4* e4=(const float4*)(yA + r*20);
      float4 q0=e4[0],q1=e4[1],q2=e4[2],q3=e4[3],q4=e4[4];
      e[0]=q0.x;e[1]=q0.y;e[2]=q0.z;e[3]=q0.w; e[4]=q1.x;e[5]=q1.y;e[6]=q1.z;e[7]=q1.w;
      e[8]=q2.x;e[9]=q2.y;e[10]=q2.z;e[11]=q2.w; e[12]=q3.x;e[13]=q3.y;e[14]=q3.z;e[15]=q3.w;
      e[16]=q4.x;e[17]=q4.y;e[18]=q4.z;e[19]=q4.w; }
    int oA=2*p, oB=2*p+1;
    const float* wA = wts + 1240 + oA*20;   // 440 + 2*400
    const float* wB = wA + 20;
    float a0 = wts[1680+oA], a1 = wts[1680+oB];
    #pragma unroll
    for(int f=0;f<20;f++){ a0 += e[f]*wA[f]; a1 += e[f]*wB[f]; }
    xhp[r*20+p] = bf16pack(softplus_f(a0), softplus_f(a1));
  }
  __syncthreads();

  // ---- ph6: sv tile for own 16 atoms (arena: wts/env1/yA now dead)
  if (t < 320){
    int a = t/20, s = t%20;
    const float2* ivr = ivcu + (abase + a)*DEG;
    float* svr = sv_s + a*652;
    float sz = (float)s*DZ;
    for(int k=0;k<32;k++){
      float2 vc = ivr[k];
      float z = (vc.x-0.2f)*Z0F - sz;
      svr[k*20+s] = vc.y*__expf(-0.5f*z*z);
    }
  }
  __syncthreads();

  // ---- ph7: env accumulate; thread=(a,f2); X from xhp, sv broadcast from LDS
  float accE[20][2];
  unsigned selfp = 0;
  if (t < 320){
    int a = t/20, f2 = t%20;
    int a_own = j*16 + a;
    #pragma unroll
    for(int s=0;s<20;s++){ accE[s][0]=0.f; accE[s][1]=0.f; }
    const float* svr = sv_s + a*652;
    const unsigned char* nbr = nb8 + a_own*32;
    for(int k=0;k<32;k++){
      unsigned xp = xhp[nbr[k]*20 + f2];
      float xlo = __uint_as_float(xp<<16);
      float xhi = __uint_as_float(xp & 0xffff0000u);
      const float4* sq = (const float4*)(svr + k*20);
      float4 q0=sq[0],q1=sq[1],q2=sq[2],q3=sq[3],q4=sq[4];
      float sv[20]={q0.x,q0.y,q0.z,q0.w, q1.x,q1.y,q1.z,q1.w,
                    q2.x,q2.y,q2.z,q2.w, q3.x,q3.y,q3.z,q3.w,
                    q4.x,q4.y,q4.z,q4.w};
      #pragma unroll
      for(int s=0;s<20;s++){ accE[s][0] += sv[s]*xlo; accE[s][1] += sv[s]*xhi; }
    }
    selfp = xhp[a_own*20 + f2];
  }
  __syncthreads();      // sv reads complete; er overlays sv

  // ---- ph8: pack er (A operand, K=864): k=s*40+f rows, self k=800+f, pad 0
  if (t < 320){
    int a = t/20, f2 = t%20;
    unsigned* e = er + a*436;
    #pragma unroll
    for(int s=0;s<20;s++) e[s*20+f2] = bf16pack(accE[s][0], accE[s][1]);
    e[400+f2] = selfp;
  }
  if (t < 256) er[(t>>4)*436 + 420 + (t&15)] = 0u;
  __syncthreads();

  // ---- ph9: MFMA GEMM K=864, 5 waves x 16-wide g-tiles (verified r4-r6)
  if (t < 320){
    int wv = t >> 6, l = t & 63;
    f32x4 cacc = {0.f,0.f,0.f,0.f};
    const unsigned* abase_p = er + (l & 15)*436 + ((l>>4)<<2);
    const short8v* bptr = (const short8v*)Wmf + (wv*64 + l);
    #pragma unroll 3
    for(int slab=0; slab<27; ++slab){
      short8v av = *(const short8v*)(abase_p + slab*16);
      short8v bv = bptr[slab*320];
      cacc = __builtin_amdgcn_mfma_f32_16x16x32_bf16(av, bv, cacc, 0,0,0);
    }
    int g = wv*16 + (l & 15);
    float wb = Wb[g];
    int r0 = (l>>4)*4;
    #pragma unroll
    for(int r=0;r<4;r++) tmp_s[(r0+r)*80 + g] = cacc[r] + wb;
  }
  __syncthreads();

  // ---- ph10: LSTM gates + h/c update + projection pieces
  if (t < 320){
    int a = t/20, u = t%20;
    int atom = abase + a;
    float4 tv = *(const float4*)(tmp_s + a*80 + u*4);
    float cold = ct[atom*20+u];
    float cnew = sigmoid_f(tv.y)*cold + sigmoid_f(tv.x)*tanh_f(tv.z);
    float og   = sigmoid_f(tv.w);
    ct[atom*20+u]   = cnew;
    hout[atom*20+u] = og*tanh_f(cnew);
    red_s[a*20+u]   = og*pw1[u];
  }
  __syncthreads();
  if (t < 320 && (t%20)==0){
    int a = t/20, atom = abase + a;
    float accx = proj0[atom];
    #pragma unroll
    for(int u=0;u<20;u++) accx += red_s[a*20+u];
    x0[atom] = accx;
    if(out_col>=0) outp[atom*3+out_col] = accx;
  }
}

extern "C" void kernel_launch(void* const* d_in, const int* in_sizes, int n_in,
                              void* d_out, int out_size, void* d_ws, size_t ws_size,
                              hipStream_t stream)
{
  const int*   species = (const int*)  d_in[0];
  const float* coord   = (const float*)d_in[1];
  const float* xh      = (const float*)d_in[2];
  const float* xraw    = (const float*)d_in[3];
  const int*   pf      = (const int*)  d_in[4];
  const int*   ps      = (const int*)  d_in[5];
  const float* h0_intw = (const float*)d_in[6];
  const float* h0_sw   = (const float*)d_in[7];
  const float* h0_sb   = (const float*)d_in[8];
  const float* h0_aw   = (const float*)d_in[9];
  const float* h0_ab   = (const float*)d_in[10];
  const float* h1_intw = (const float*)d_in[11];
  const float* h1_sw   = (const float*)d_in[12];
  const float* h1_sb   = (const float*)d_in[13];
  const float* h1_aw   = (const float*)d_in[14];
  const float* h1_ab   = (const float*)d_in[15];
  const float* W_intw  = (const float*)d_in[16];
  const float* W_sw    = (const float*)d_in[17];
  const float* W_sb    = (const float*)d_in[18];
  const float* pw0     = (const float*)d_in[19];
  const float* pw1     = (const float*)d_in[20];
  const float* pb1     = (const float*)d_in[21];
  float* outp = (float*)d_out;

  float* w = (float*)d_ws;
  float2* ivcu_g = (float2*)w;  w += 2*NP;
  float* indf = w;  w += NA*5;
  float* proj0= w;  w += NA;
  float* hA   = w;  w += NA*20;
  float* hB   = w;  w += NA*20;
  float* ct   = w;  w += NA*20;
  float* x0A  = w;  w += NA;
  float* x0B  = w;  w += NA;
  bf16*  Wmf  = (bf16*)w;              // 69120 bf16

  k_setup<<<512,256,0,stream>>>(pf,ps,species,coord,xh,pw0,pb1,W_intw,W_sw,
                                ivcu_g,indf,proj0,Wmf);
  k_f0<<<1024,256,0,stream>>>(ps,ivcu_g,indf,h0_intw,h0_sw,h0_sb,h0_aw,h0_ab,
                              ct,hA);

  const float* hin = hA; float* ho = hB;
  const float* x0i = x0A; float* x0o = x0B;
  for(int step=0; step<5; ++step){
    int use_raw = (step<2)?1:0;
    int col = (step<2)? step : 0;
    int out_col = (step>=2)? (step-2) : -1;
    k_step<<<256,512,0,stream>>>(ps, ivcu_g, xraw, x0i, use_raw, col,
                                 h1_intw, h1_sw, h1_sb, h1_aw, h1_ab,
                                 hin, Wmf, W_sb, pw1, proj0,
                                 ct, ho, x0o, outp, out_col);
    const float* ts = hin; hin = ho; ho = (float*)ts;
    const float* tx = x0i; x0i = x0o; x0o = (float*)tx;
  }
}